// Round 2
// baseline (5669.110 us; speedup 1.0000x reference)
//
#include <hip/hip_runtime.h>
#include <math.h>

#define BB    256
#define NN_   128
#define XD    8
#define YD    8
#define ZD    64
#define RD    128
#define HID   256
#define NSTEPS 50
#define NT    8          // rows per decode tile
#define NTILES (NN_/NT)
#define PADD  260        // double-stride padding (h tile)
#define PADF  260        // float-stride padding (gp, wd2t)

// jax.nn.gelu (approximate=True), full double precision
__device__ __forceinline__ double gelu_d(double x) {
    const double c = 0.7978845608028653558798921198687637; // sqrt(2/pi)
    const double a = 0.044715;
    double u = c * x * (1.0 + a * x * x);
    double T = tanh(u);
    return 0.5 * x * (1.0 + T);
}

__device__ __forceinline__ void gelu_both_d(double x, double& h, double& gp) {
    const double c = 0.7978845608028653558798921198687637;
    const double a = 0.044715;
    double x2 = x * x;
    double u  = c * x * (1.0 + a * x2);
    double T  = tanh(u);
    double hp = 0.5 * (1.0 + T);
    h  = hp * x;
    gp = hp + x * (0.5 * (1.0 - T * T)) * c * (1.0 + 3.0 * a * x2);
}

__global__ __launch_bounds__(256) void nets_sampler_kernel(
    const float* __restrict__ x_ctx, const float* __restrict__ y_ctx,
    const float* __restrict__ mask,  const float* __restrict__ z0,
    const float* __restrict__ noise,
    const float* __restrict__ We1, const float* __restrict__ be1,
    const float* __restrict__ We2, const float* __restrict__ be2,
    const float* __restrict__ Wd1, const float* __restrict__ bd1,
    const float* __restrict__ Wd2, const float* __restrict__ bd2,
    const float* __restrict__ Wb1, const float* __restrict__ bb1,
    const float* __restrict__ Wb2, const float* __restrict__ bb2,
    float* __restrict__ out)
{
    const int b   = blockIdx.x;
    const int tid = threadIdx.x;           // hidden column j (0..255)

    __shared__ __align__(16) float x_s[NN_][XD];
    __shared__ __align__(16) float y_s[NN_][YD];
    __shared__ float  m_s[NN_];
    __shared__ double h_t[NT][PADD];       // decode hidden tile (f64)
    __shared__ float  gp_t[NT][PADF];      // gelu' tile (f32, one benign rounding)
    __shared__ float  wd2t[YD][PADF];      // Wd2 transposed (exact f32)
    __shared__ double pm[4][NT][YD];       // mu partials per j-quarter
    __shared__ double res_d[NT][YD];
    __shared__ double z_ds[ZD];            // z state (f64)
    __shared__ double hb_ds[HID];          // drift hidden / pooled scratch
    __shared__ double bp_d[4][ZD];
    __shared__ double gzw[4][ZD];
    __shared__ double r_d[RD];
    __shared__ double rp2[2][RD];
    __shared__ double bd2_d[YD];
    __shared__ double bb2_d[ZD];

    // ---------------- load context (exact f32) ----------------
    {
        const float4* xg = reinterpret_cast<const float4*>(x_ctx + (size_t)b * NN_ * XD);
        reinterpret_cast<float4*>(&x_s[0][0])[tid] = xg[tid];
        const float4* yg = reinterpret_cast<const float4*>(y_ctx + (size_t)b * NN_ * YD);
        reinterpret_cast<float4*>(&y_s[0][0])[tid] = yg[tid];
        if (tid < NN_) m_s[tid]  = mask[(size_t)b * NN_ + tid];
        if (tid < ZD)  z_ds[tid] = (double)z0[(size_t)b * ZD + tid];
        if (tid < YD)  bd2_d[tid] = (double)bd2[tid];
        if (tid < ZD)  bb2_d[tid] = (double)bb2[tid];
    }

    // ---------------- per-thread weights (exact f32 / f64) ----------------
    float wd1z[64];                        // Wd1 z-rows, column j
#pragma unroll
    for (int k = 0; k < 64; k++) wd1z[k] = Wd1[(8 + k) * HID + tid];
    double wd1x_d[8];                      // Wd1 x-rows, column j (f64, exact cvt)
#pragma unroll
    for (int k = 0; k < 8; k++) wd1x_d[k] = (double)Wd1[k * HID + tid];

    float wd2r[8];                         // Wd2[j,:]
    {
        float4 a0 = reinterpret_cast<const float4*>(Wd2 + (size_t)tid * 8)[0];
        float4 a1 = reinterpret_cast<const float4*>(Wd2 + (size_t)tid * 8)[1];
        wd2r[0] = a0.x; wd2r[1] = a0.y; wd2r[2] = a0.z; wd2r[3] = a0.w;
        wd2r[4] = a1.x; wd2r[5] = a1.y; wd2r[6] = a1.z; wd2r[7] = a1.w;
    }
#pragma unroll
    for (int yd = 0; yd < 8; yd++) wd2t[yd][tid] = wd2r[yd];

    const double bd1_d  = (double)bd1[tid];
    const double wb1t_d = (double)Wb1[(ZD + RD) * HID + tid];   // t row (192)

    float we1r[16];
#pragma unroll
    for (int k = 0; k < 16; k++) we1r[k] = We1[k * HID + tid];
    const double be1_d = (double)be1[tid];

    __syncthreads();

    // ---------------- encoder (once, f64) ----------------
    double msum = 0.0;
    for (int n = 0; n < NN_; n++) msum += (double)m_s[n];
    msum = fmax(msum, 1.0);

    double pacc = 0.0;
    for (int n = 0; n < NN_; n++) {
        double pre = be1_d;
#pragma unroll
        for (int k = 0; k < 8; k++) pre += (double)x_s[n][k] * (double)we1r[k];
#pragma unroll
        for (int k = 0; k < 8; k++) pre += (double)y_s[n][k] * (double)we1r[8 + k];
        pacc += gelu_d(pre) * (double)m_s[n];
    }
    hb_ds[tid] = pacc / msum;              // pooled
    __syncthreads();
    {
        int i = tid & 127, half = tid >> 7;
        double racc = 0.0;
        for (int jj = half * 128; jj < half * 128 + 128; jj++)
            racc += hb_ds[jj] * (double)We2[jj * RD + i];
        rp2[half][i] = racc;
    }
    __syncthreads();
    if (tid < RD) r_d[tid] = rp2[0][tid] + rp2[1][tid] + (double)be2[tid];
    __syncthreads();

    // step-invariant drift hidden part: bb1 + r @ Wb1[r-rows]
    double hbr = (double)bb1[tid];
    for (int k = 0; k < RD; k++) hbr += r_d[k] * (double)Wb1[(ZD + k) * HID + tid];

    // ---------------- main loop ----------------
    const double dt  = 1.0 / (double)NSTEPS;
    const double nsc = sqrt(2.0 * 1.0 * dt);      // EPSILON = 1

    for (int s = 0; s < NSTEPS; s++) {
        const double t = (double)s * dt;

        // ---- A: zdot (once per step!) + drift hidden ----
        double zdot = 0.0;
#pragma unroll 8
        for (int k = 0; k < 64; k++) zdot += z_ds[k] * (double)wd1z[k];

        {
            double hacc = hbr + t * wb1t_d;
#pragma unroll 8
            for (int k = 0; k < 64; k++) hacc += z_ds[k] * (double)Wb1[k * HID + tid];
            hb_ds[tid] = gelu_d(hacc);
        }
        __syncthreads();

        // ---- drift output partials ----
        {
            int kk = tid & 63, c = tid >> 6;
            double acc = 0.0;
            for (int j = c * 64; j < c * 64 + 64; j++)
                acc += hb_ds[j] * (double)Wb2[j * ZD + kk];
            bp_d[c][kk] = acc;
        }

        // ---- decode fwd + bwd, 16 tiles of 8 rows ----
        double S = 0.0;                    // sum_n dpre[n][j]
        const double zpre = bd1_d + zdot;  // n-invariant part of pre

        for (int tile = 0; tile < NTILES; tile++) {
            const int base = tile * NT;
            // F
            for (int nn = 0; nn < NT; nn++) {
                double pre = zpre;
#pragma unroll
                for (int k = 0; k < 8; k++)
                    pre += (double)x_s[base + nn][k] * wd1x_d[k];
                double h, gp;
                gelu_both_d(pre, h, gp);
                h_t[nn][tid]  = h;
                gp_t[nn][tid] = (float)gp;
            }
            __syncthreads();
            // M: mu partials over j-quarters
            {
                int q = tid >> 6, pair = tid & 63;
                int nn = pair >> 3, yd = pair & 7;
                double acc = 0.0;
#pragma unroll 8
                for (int jj = q * 64; jj < q * 64 + 64; jj++)
                    acc += h_t[nn][jj] * (double)wd2t[yd][jj];
                pm[q][nn][yd] = acc;
            }
            __syncthreads();
            // R: residual
            if (tid < NT * YD) {
                int nn = tid >> 3, yd = tid & 7;
                double mu = pm[0][nn][yd] + pm[1][nn][yd] + pm[2][nn][yd] + pm[3][nn][yd]
                          + bd2_d[yd];
                // t/sigma^2 = 4t (exact)
                res_d[nn][yd] = 4.0 * t * (mu - (double)y_s[base + nn][yd])
                                        * (double)m_s[base + nn];
            }
            __syncthreads();
            // B: S += dpre
            for (int nn = 0; nn < NT; nn++) {
                double dh = 0.0;
#pragma unroll
                for (int yd = 0; yd < 8; yd++) dh += res_d[nn][yd] * (double)wd2r[yd];
                S += dh * (double)gp_t[nn][tid];
            }
            __syncthreads();
        }

        // ---- gradient: gz[k] = sum_j wd1z[k][j]*S_j  (butterfly, f64) ----
        {
            int lane = tid & 63, w = tid >> 6;
#pragma unroll 4
            for (int k = 0; k < 64; k++) {
                double v = S * (double)wd1z[k];
                v += __shfl_xor(v, 1);
                v += __shfl_xor(v, 2);
                v += __shfl_xor(v, 4);
                v += __shfl_xor(v, 8);
                v += __shfl_xor(v, 16);
                v += __shfl_xor(v, 32);
                if (lane == k) gzw[w][k] = v;
            }
        }
        __syncthreads();

        // ---- z update (f64) ----
        if (tid < ZD) {
            double g = z_ds[tid] + gzw[0][tid] + gzw[1][tid] + gzw[2][tid] + gzw[3][tid];
            g = fmin(fmax(g, -100.0), 100.0);
            double bdrift = bp_d[0][tid] + bp_d[1][tid] + bp_d[2][tid] + bp_d[3][tid]
                          + bb2_d[tid];
            double nz = (double)noise[((size_t)s * BB + b) * ZD + tid];
            z_ds[tid] = z_ds[tid] + (bdrift - g) * dt + nsc * nz;
        }
        __syncthreads();
    }

    if (tid < ZD) out[(size_t)b * ZD + tid] = (float)z_ds[tid];
}

extern "C" void kernel_launch(void* const* d_in, const int* in_sizes, int n_in,
                              void* d_out, int out_size, void* d_ws, size_t ws_size,
                              hipStream_t stream) {
    const float* x_ctx = (const float*)d_in[0];
    const float* y_ctx = (const float*)d_in[1];
    const float* maskp = (const float*)d_in[2];
    const float* z0    = (const float*)d_in[3];
    const float* noise = (const float*)d_in[4];
    const float* We1   = (const float*)d_in[5];
    const float* be1   = (const float*)d_in[6];
    const float* We2   = (const float*)d_in[7];
    const float* be2   = (const float*)d_in[8];
    const float* Wd1   = (const float*)d_in[9];
    const float* bd1   = (const float*)d_in[10];
    const float* Wd2   = (const float*)d_in[11];
    const float* bd2   = (const float*)d_in[12];
    const float* Wb1   = (const float*)d_in[13];
    const float* bb1   = (const float*)d_in[14];
    const float* Wb2   = (const float*)d_in[15];
    const float* bb2   = (const float*)d_in[16];
    float* out = (float*)d_out;

    nets_sampler_kernel<<<BB, 256, 0, stream>>>(
        x_ctx, y_ctx, maskp, z0, noise,
        We1, be1, We2, be2, Wd1, bd1, Wd2, bd2, Wb1, bb1, Wb2, bb2, out);
}

// Round 3
// 3398.228 us; speedup vs baseline: 1.6683x; 1.6683x over previous
//
#include <hip/hip_runtime.h>
#include <math.h>

#define BB    256
#define NN_   128
#define ZD    64
#define RD    128
#define HID   256
#define NSTEPS 50
#define NT    16
#define NTILES 8
#define TPB   512
#define PADD  258   // f64 row stride: 516 words -> rows land 4 banks apart

// ---------- fast f64-accuracy exp/sigmoid/gelu (no libm, no f64 divide) ----------
__device__ __forceinline__ double fast_exp_d(double x) {
    // |x| <= 60 assumed (caller clamps)
    const double L2E   = 1.44269504088896340736;
    const double LN2HI = 6.93147180369123816490e-01;   // 33 significant bits
    const double LN2LO = 1.90821492927058770002e-10;
    const double MAGIC = 6755399441055744.0;           // 1.5*2^52
    double vn = fma(x, L2E, MAGIC);
    int ni = __double2loint(vn);
    double n = vn - MAGIC;
    double r = fma(n, -LN2HI, x);
    r = fma(n, -LN2LO, r);
    double p = 2.50521083854417187751e-08;             // 1/11!
    p = fma(p, r, 2.75573192239858906526e-07);
    p = fma(p, r, 2.75573192239858906526e-06);
    p = fma(p, r, 2.48015873015873015873e-05);
    p = fma(p, r, 1.98412698412698412698e-04);
    p = fma(p, r, 1.38888888888888888889e-03);
    p = fma(p, r, 8.33333333333333333333e-03);
    p = fma(p, r, 4.16666666666666666667e-02);
    p = fma(p, r, 1.66666666666666666667e-01);
    p = fma(p, r, 0.5);
    p = fma(p, r, 1.0);
    p = fma(p, r, 1.0);
    return p * __hiloint2double((1023 + ni) << 20, 0);
}

__device__ __forceinline__ double sigmoid_d(double w) {
    double wc = fmin(fmax(w, -60.0), 60.0);
    double e = fast_exp_d(-wc);
    double d = 1.0 + e;
    float r0 = __builtin_amdgcn_rcpf((float)d);
    double y = (double)r0;
    y = fma(y, fma(-d, y, 1.0), y);     // 2 Newton steps: err ~1e-20
    y = fma(y, fma(-d, y, 1.0), y);
    return y;
}

__device__ __forceinline__ double gelu_d(double x) {
    const double c2 = 1.59576912160573071176;  // 2*sqrt(2/pi)
    double w = c2 * x * fma(0.044715, x * x, 1.0);
    return x * sigmoid_d(w);
}

__device__ __forceinline__ void gelu_both_d(double x, double& h, double& gp) {
    const double c  = 0.79788456080286535588;
    const double a  = 0.044715;
    double x2 = x * x;
    double w  = (2.0 * c) * x * fma(a, x2, 1.0);
    double hp = sigmoid_d(w);
    h = x * hp;
    double s = hp * (1.0 - hp);                // 0.25*(1-T^2) scaled: 1-T^2 = 4hp(1-hp)
    gp = fma(x * s, (2.0 * c) * fma(3.0 * a, x2, 1.0), hp);
}

// ---------- dynamic LDS layout (~153 KB) ----------
struct Smem {
    double h_t[NT][PADD];        // decode hidden tile (f64)
    double wd2t_d[8][PADD];      // Wd2 transposed (f64)
    double z_ds[ZD];             // z state
    double hb_ds[HID];           // pooled / drift hidden / Ssum
    double scratch2[2][HID];     // rp2 / hpart / Sp
    double pmgz[512];            // pm[4][16][8] / gzp[8][64]
    double res_r[NT][8];         // residual tile / r_d[128]
    double bp_d[8][ZD];          // drift-out partials
    double bd2_d[8];
    double bb2_d[ZD];
    float  gp_t[NT][HID];        // gelu' tile (f32, benign)
    float  x_s[NN_][8];
    float  y_s[NN_][8];
    float  m_s[NN_];
    float  wd1zT[HID * ZD];      // Wd1 z-block transposed, XOR-swizzled
};

__global__ __launch_bounds__(TPB, 2) void nets_sampler_kernel(
    const float* __restrict__ x_ctx, const float* __restrict__ y_ctx,
    const float* __restrict__ mask,  const float* __restrict__ z0,
    const float* __restrict__ noise,
    const float* __restrict__ We1, const float* __restrict__ be1,
    const float* __restrict__ We2, const float* __restrict__ be2,
    const float* __restrict__ Wd1, const float* __restrict__ bd1,
    const float* __restrict__ Wd2, const float* __restrict__ bd2,
    const float* __restrict__ Wb1, const float* __restrict__ bb1,
    const float* __restrict__ Wb2, const float* __restrict__ bb2,
    float* __restrict__ out)
{
    extern __shared__ char smem_raw[];
    Smem& sm = *reinterpret_cast<Smem*>(smem_raw);

    const int b   = blockIdx.x;
    const int tid = threadIdx.x;
    const int j   = tid & 255;       // hidden column
    const int g   = tid >> 8;        // row-group (0/1)
    double* r_d = &sm.res_r[0][0];   // alias: encoder r vector (pre-loop only)

    // ---------------- loads ----------------
    if (tid < 256) {
        reinterpret_cast<float4*>(&sm.x_s[0][0])[tid] =
            reinterpret_cast<const float4*>(x_ctx + (size_t)b * NN_ * 8)[tid];
        reinterpret_cast<float4*>(&sm.y_s[0][0])[tid] =
            reinterpret_cast<const float4*>(y_ctx + (size_t)b * NN_ * 8)[tid];
    }
    if (tid < NN_) sm.m_s[tid] = mask[(size_t)b * NN_ + tid];
    if (tid < ZD) {
        sm.z_ds[tid]  = (double)z0[(size_t)b * ZD + tid];
        sm.bb2_d[tid] = (double)bb2[tid];
    }
    if (tid < 8) sm.bd2_d[tid] = (double)bd2[tid];

    float wd1z[64];                      // Wd1 z-rows, column j (exact f32)
#pragma unroll
    for (int k = 0; k < 64; k++) wd1z[k] = Wd1[(8 + k) * HID + j];
    double wd1x_d[8];
#pragma unroll
    for (int k = 0; k < 8; k++) wd1x_d[k] = (double)Wd1[k * HID + j];

    double wd2r_d[8];
    {
        float4 a0 = reinterpret_cast<const float4*>(Wd2 + (size_t)j * 8)[0];
        float4 a1 = reinterpret_cast<const float4*>(Wd2 + (size_t)j * 8)[1];
        wd2r_d[0] = (double)a0.x; wd2r_d[1] = (double)a0.y;
        wd2r_d[2] = (double)a0.z; wd2r_d[3] = (double)a0.w;
        wd2r_d[4] = (double)a1.x; wd2r_d[5] = (double)a1.y;
        wd2r_d[6] = (double)a1.z; wd2r_d[7] = (double)a1.w;
    }
    if (g == 0) {
#pragma unroll
        for (int yd = 0; yd < 8; yd++) sm.wd2t_d[yd][j] = wd2r_d[yd];
#pragma unroll
        for (int kk = 0; kk < 32; kk++)
            sm.wd1zT[j * 64 + (kk ^ (j & 63))] = wd1z[kk];
    } else {
#pragma unroll
        for (int kk = 0; kk < 32; kk++)
            sm.wd1zT[j * 64 + ((32 + kk) ^ (j & 63))] = wd1z[32 + kk];
    }
    const double bd1_d = (double)bd1[j];

    __syncthreads();

    // ---------------- encoder (once, f64) ----------------
    if (tid < 256) {
        float we1r[16];
#pragma unroll
        for (int k = 0; k < 16; k++) we1r[k] = We1[k * HID + j];
        double be1_d = (double)be1[j];
        double msum = 0.0;
        for (int n = 0; n < NN_; n++) msum += (double)sm.m_s[n];
        msum = fmax(msum, 1.0);
        double pacc = 0.0;
        for (int n = 0; n < NN_; n++) {
            double pre = be1_d;
#pragma unroll
            for (int k = 0; k < 8; k++) pre = fma((double)sm.x_s[n][k], (double)we1r[k], pre);
#pragma unroll
            for (int k = 0; k < 8; k++) pre = fma((double)sm.y_s[n][k], (double)we1r[8 + k], pre);
            pacc += gelu_d(pre) * (double)sm.m_s[n];
        }
        sm.hb_ds[j] = pacc / msum;       // pooled
    }
    __syncthreads();
    if (tid < 256) {
        int i = tid & 127, half = tid >> 7;
        double racc = 0.0;
        for (int jj = half * 128; jj < half * 128 + 128; jj++)
            racc = fma(sm.hb_ds[jj], (double)We2[jj * RD + i], racc);
        sm.scratch2[half][i] = racc;
    }
    __syncthreads();
    if (tid < RD) r_d[tid] = sm.scratch2[0][tid] + sm.scratch2[1][tid] + (double)be2[tid];
    __syncthreads();

    double hbr = 0.0, wb1t_d = 0.0;
    if (tid < 256) {                     // step-invariant drift-hidden part
        hbr = (double)bb1[j];
        for (int k = 0; k < RD; k++)
            hbr = fma(r_d[k], (double)Wb1[(ZD + k) * HID + j], hbr);
        wb1t_d = (double)Wb1[(ZD + RD) * HID + j];
    }
    __syncthreads();                     // r_d (res_r alias) free after this

    // ---------------- main 50-step loop ----------------
    const double dt  = 1.0 / (double)NSTEPS;
    const double nsc = sqrt(2.0 * 1.0 * dt);

    for (int s = 0; s < NSTEPS; s++) {
        const double t = (double)s * dt;

        // zdot (per-thread, step-invariant x-part is in tiles)
        double zd0 = 0.0, zd1 = 0.0;
#pragma unroll
        for (int k = 0; k < 64; k += 2) {
            zd0 = fma(sm.z_ds[k],     (double)wd1z[k],     zd0);
            zd1 = fma(sm.z_ds[k + 1], (double)wd1z[k + 1], zd1);
        }
        const double zpre = bd1_d + zd0 + zd1;

        // ---- phase A: drift hidden partials (k-split across g) ----
        {
            double a0 = 0.0;
            if (g == 0) {
#pragma unroll
                for (int kk = 0; kk < 32; kk++)
                    a0 = fma(sm.z_ds[kk], (double)Wb1[kk * HID + j], a0);
            } else {
#pragma unroll
                for (int kk = 0; kk < 32; kk++)
                    a0 = fma(sm.z_ds[32 + kk], (double)Wb1[(32 + kk) * HID + j], a0);
            }
            sm.scratch2[g][j] = a0;
        }
        __syncthreads();
        if (tid < 256) {
            double hacc = hbr + t * wb1t_d + sm.scratch2[0][j] + sm.scratch2[1][j];
            sm.hb_ds[j] = gelu_d(hacc);
        }
        __syncthreads();
        // ---- drift out partials (no trailing sync needed; consumed at update) ----
        {
            int kk = tid & 63, c = tid >> 6;
            double acc = 0.0;
            for (int jj = c * 32; jj < c * 32 + 32; jj++)
                acc = fma(sm.hb_ds[jj], (double)Wb2[jj * ZD + kk], acc);
            sm.bp_d[c][kk] = acc;
        }

        // ---- decode fwd+bwd: 8 tiles x 16 rows (rows split across g) ----
        double S = 0.0;                  // sum_n dpre[n][j] (this thread's row-half)
        for (int tile = 0; tile < NTILES; tile++) {
            const int base = tile * NT;
            const int rb = g * 8;
            // F: hidden + gelu'
#pragma unroll
            for (int nn = 0; nn < 8; nn++) {
                const int row = rb + nn;
                const float4 xa = *reinterpret_cast<const float4*>(&sm.x_s[base + row][0]);
                const float4 xb = *reinterpret_cast<const float4*>(&sm.x_s[base + row][4]);
                double pre = zpre;
                pre = fma((double)xa.x, wd1x_d[0], pre);
                pre = fma((double)xa.y, wd1x_d[1], pre);
                pre = fma((double)xa.z, wd1x_d[2], pre);
                pre = fma((double)xa.w, wd1x_d[3], pre);
                pre = fma((double)xb.x, wd1x_d[4], pre);
                pre = fma((double)xb.y, wd1x_d[5], pre);
                pre = fma((double)xb.z, wd1x_d[6], pre);
                pre = fma((double)xb.w, wd1x_d[7], pre);
                double h, gp;
                gelu_both_d(pre, h, gp);
                sm.h_t[row][j]  = h;
                sm.gp_t[row][j] = (float)gp;
            }
            __syncthreads();
            // M: mu partials over j-quarters (double2 LDS reads, conflict-free)
            {
                const int q = tid >> 7, pair = tid & 127;
                const int nn = pair >> 3, yd = pair & 7;
                const double2* hrow = reinterpret_cast<const double2*>(&sm.h_t[nn][q * 64]);
                const double2* wrow = reinterpret_cast<const double2*>(&sm.wd2t_d[yd][q * 64]);
                double a0 = 0.0, a1 = 0.0;
#pragma unroll
                for (int i = 0; i < 32; i++) {
                    double2 hv = hrow[i], wv = wrow[i];
                    a0 = fma(hv.x, wv.x, a0);
                    a1 = fma(hv.y, wv.y, a1);
                }
                sm.pmgz[q * 128 + pair] = a0 + a1;
            }
            __syncthreads();
            // R: residual
            if (tid < 128) {
                const int nn = tid >> 3, yd = tid & 7;
                double mu = sm.pmgz[tid] + sm.pmgz[128 + tid] + sm.pmgz[256 + tid]
                          + sm.pmgz[384 + tid] + sm.bd2_d[yd];
                sm.res_r[nn][yd] = 4.0 * t * (mu - (double)sm.y_s[base + nn][yd])
                                           * (double)sm.m_s[base + nn];
            }
            __syncthreads();
            // B: S += dpre over this thread's row-half
#pragma unroll
            for (int nn = 0; nn < 8; nn++) {
                const int row = rb + nn;
                const double2* rr = reinterpret_cast<const double2*>(&sm.res_r[row][0]);
                double2 r0 = rr[0], r1 = rr[1], r2 = rr[2], r3 = rr[3];
                double dh = r0.x * wd2r_d[0] + r0.y * wd2r_d[1]
                          + r1.x * wd2r_d[2] + r1.y * wd2r_d[3]
                          + r2.x * wd2r_d[4] + r2.y * wd2r_d[5]
                          + r3.x * wd2r_d[6] + r3.y * wd2r_d[7];
                S = fma(dh, (double)sm.gp_t[row][j], S);
            }
            __syncthreads();
        }

        // ---- gradient: gz[k] = sum_j Ssum_j * Wd1z[k][j] via LDS matvec ----
        sm.scratch2[g][j] = S;
        __syncthreads();
        if (tid < 256) sm.hb_ds[j] = sm.scratch2[0][j] + sm.scratch2[1][j];  // Ssum
        __syncthreads();
        {
            const int k = tid & 63, c = tid >> 6;
            double acc = 0.0;
#pragma unroll
            for (int i = 0; i < 32; i++) {
                const int jj = c * 32 + i;
                acc = fma(sm.hb_ds[jj],
                          (double)sm.wd1zT[jj * 64 + (k ^ (jj & 63))], acc);
            }
            sm.pmgz[c * 64 + k] = acc;   // gzp
        }
        __syncthreads();
        // ---- z update ----
        if (tid < ZD) {
            double gsum = sm.z_ds[tid];
#pragma unroll
            for (int c = 0; c < 8; c++) gsum += sm.pmgz[c * 64 + tid];
            gsum = fmin(fmax(gsum, -100.0), 100.0);
            double bdr = sm.bb2_d[tid];
#pragma unroll
            for (int c = 0; c < 8; c++) bdr += sm.bp_d[c][tid];
            double nz = (double)noise[((size_t)s * BB + b) * ZD + tid];
            sm.z_ds[tid] = sm.z_ds[tid] + (bdr - gsum) * dt + nsc * nz;
        }
        __syncthreads();
    }

    if (tid < ZD) out[(size_t)b * ZD + tid] = (float)sm.z_ds[tid];
}

extern "C" void kernel_launch(void* const* d_in, const int* in_sizes, int n_in,
                              void* d_out, int out_size, void* d_ws, size_t ws_size,
                              hipStream_t stream) {
    const float* x_ctx = (const float*)d_in[0];
    const float* y_ctx = (const float*)d_in[1];
    const float* maskp = (const float*)d_in[2];
    const float* z0    = (const float*)d_in[3];
    const float* noise = (const float*)d_in[4];
    const float* We1   = (const float*)d_in[5];
    const float* be1   = (const float*)d_in[6];
    const float* We2   = (const float*)d_in[7];
    const float* be2   = (const float*)d_in[8];
    const float* Wd1   = (const float*)d_in[9];
    const float* bd1   = (const float*)d_in[10];
    const float* Wd2   = (const float*)d_in[11];
    const float* bd2   = (const float*)d_in[12];
    const float* Wb1   = (const float*)d_in[13];
    const float* bb1   = (const float*)d_in[14];
    const float* Wb2   = (const float*)d_in[15];
    const float* bb2   = (const float*)d_in[16];
    float* out = (float*)d_out;

    // allow >64KB dynamic LDS (gfx950 has 160KB/CU); ignore return defensively
    (void)hipFuncSetAttribute((const void*)nets_sampler_kernel,
                              hipFuncAttributeMaxDynamicSharedMemorySize,
                              (int)sizeof(Smem));

    nets_sampler_kernel<<<BB, TPB, sizeof(Smem), stream>>>(
        x_ctx, y_ctx, maskp, z0, noise,
        We1, be1, We2, be2, Wd1, bd1, Wd2, bd2, Wb1, bb1, Wb2, bb2, out);
}

// Round 4
// 3330.532 us; speedup vs baseline: 1.7022x; 1.0203x over previous
//
#include <hip/hip_runtime.h>
#include <math.h>

#define BB    256
#define NN_   128
#define ZD    64
#define RD    128
#define HID   256
#define NSTEPS 50
#define NT    16
#define NTILES 8
#define TPB   512
#define PADD  258   // f64 row stride: 516 words -> rows land 4 banks apart

// ---------- fast f64-accuracy exp/sigmoid/gelu (no libm, no f64 divide) ----------
__device__ __forceinline__ double fast_exp_d(double x) {
    // |x| <= 60 assumed (caller clamps)
    const double L2E   = 1.44269504088896340736;
    const double LN2HI = 6.93147180369123816490e-01;   // 33 significant bits
    const double LN2LO = 1.90821492927058770002e-10;
    const double MAGIC = 6755399441055744.0;           // 1.5*2^52
    double vn = fma(x, L2E, MAGIC);
    int ni = __double2loint(vn);
    double n = vn - MAGIC;
    double r = fma(n, -LN2HI, x);
    r = fma(n, -LN2LO, r);
    double p = 2.50521083854417187751e-08;             // 1/11!
    p = fma(p, r, 2.75573192239858906526e-07);
    p = fma(p, r, 2.75573192239858906526e-06);
    p = fma(p, r, 2.48015873015873015873e-05);
    p = fma(p, r, 1.98412698412698412698e-04);
    p = fma(p, r, 1.38888888888888888889e-03);
    p = fma(p, r, 8.33333333333333333333e-03);
    p = fma(p, r, 4.16666666666666666667e-02);
    p = fma(p, r, 1.66666666666666666667e-01);
    p = fma(p, r, 0.5);
    p = fma(p, r, 1.0);
    p = fma(p, r, 1.0);
    return p * __hiloint2double((1023 + ni) << 20, 0);
}

__device__ __forceinline__ double sigmoid_d(double w) {
    double wc = fmin(fmax(w, -60.0), 60.0);
    double e = fast_exp_d(-wc);
    double d = 1.0 + e;
    float r0 = __builtin_amdgcn_rcpf((float)d);
    double y = (double)r0;
    y = fma(y, fma(-d, y, 1.0), y);     // 2 Newton steps: err ~1e-20
    y = fma(y, fma(-d, y, 1.0), y);
    return y;
}

__device__ __forceinline__ double gelu_d(double x) {
    const double c2 = 1.59576912160573071176;  // 2*sqrt(2/pi)
    double w = c2 * x * fma(0.044715, x * x, 1.0);
    return x * sigmoid_d(w);
}

__device__ __forceinline__ void gelu_both_d(double x, double& h, double& gp) {
    const double c  = 0.79788456080286535588;
    const double a  = 0.044715;
    double x2 = x * x;
    double w  = (2.0 * c) * x * fma(a, x2, 1.0);
    double hp = sigmoid_d(w);
    h = x * hp;
    double s = hp * (1.0 - hp);                // 1-T^2 = 4hp(1-hp)
    gp = fma(x * s, (2.0 * c) * fma(3.0 * a, x2, 1.0), hp);
}

// ---------- dynamic LDS layout (~153 KB) ----------
struct Smem {
    double h_t[NT][PADD];        // decode hidden tile (f64)
    double wd2t_d[8][PADD];      // Wd2 transposed (f64)
    double z_ds[ZD];             // z state
    double hb_ds[HID];           // pooled / drift hidden / Ssum
    double scratch2[2][HID];     // rp2 / hpart / Sp
    double pmgz[512];            // pm[4][16][8] / gzp[8][64]
    double res_r[NT][8];         // residual tile / r_d[128]
    double bp_d[8][ZD];          // drift-out partials
    double bd2_d[8];
    double bb2_d[ZD];
    float  gp_t[NT][HID];        // gelu' tile (f32, benign — verified r2/r3)
    float  x_s[NN_][8];
    float  y_s[NN_][8];
    float  m_s[NN_];
    float  wd1zT[HID * ZD];      // Wd1 z-block transposed, XOR-swizzled
};

__global__ __launch_bounds__(TPB, 2) void nets_sampler_kernel(
    const float* __restrict__ x_ctx, const float* __restrict__ y_ctx,
    const float* __restrict__ mask,  const float* __restrict__ z0,
    const float* __restrict__ noise,
    const float* __restrict__ We1, const float* __restrict__ be1,
    const float* __restrict__ We2, const float* __restrict__ be2,
    const float* __restrict__ Wd1, const float* __restrict__ bd1,
    const float* __restrict__ Wd2, const float* __restrict__ bd2,
    const float* __restrict__ Wb1, const float* __restrict__ bb1,
    const float* __restrict__ Wb2, const float* __restrict__ bb2,
    float* __restrict__ out)
{
    extern __shared__ char smem_raw[];
    Smem& sm = *reinterpret_cast<Smem*>(smem_raw);

    const int b   = blockIdx.x;
    const int tid = threadIdx.x;
    const int j   = tid & 255;       // hidden column
    const int g   = tid >> 8;        // row-group (0/1)
    double* r_d = &sm.res_r[0][0];   // alias: encoder r vector (pre-loop only)

    // ---------------- loads ----------------
    if (tid < 256) {
        reinterpret_cast<float4*>(&sm.x_s[0][0])[tid] =
            reinterpret_cast<const float4*>(x_ctx + (size_t)b * NN_ * 8)[tid];
        reinterpret_cast<float4*>(&sm.y_s[0][0])[tid] =
            reinterpret_cast<const float4*>(y_ctx + (size_t)b * NN_ * 8)[tid];
    }
    if (tid < NN_) sm.m_s[tid] = mask[(size_t)b * NN_ + tid];
    if (tid < ZD) {
        sm.z_ds[tid]  = (double)z0[(size_t)b * ZD + tid];
        sm.bb2_d[tid] = (double)bb2[tid];
    }
    if (tid < 8) sm.bd2_d[tid] = (double)bd2[tid];

    float wd1z[64];                      // Wd1 z-rows, column j (exact f32)
#pragma unroll
    for (int k = 0; k < 64; k++) wd1z[k] = Wd1[(8 + k) * HID + j];
    double wd1x_d[8];
#pragma unroll
    for (int k = 0; k < 8; k++) wd1x_d[k] = (double)Wd1[k * HID + j];

    // ---- per-step drift weights -> REGISTERS (kills 1.6 GB of re-fetch) ----
    float wb1_r[32];                     // Wb1 z-rows (g-split), column j
#pragma unroll
    for (int kk = 0; kk < 32; kk++) wb1_r[kk] = Wb1[(g * 32 + kk) * HID + j];
    const int du_k = tid & 63, du_c = tid >> 6;   // drift-out partition
    float wb2_r[32];                     // Wb2 rows du_c*32.., column du_k
#pragma unroll
    for (int i = 0; i < 32; i++) wb2_r[i] = Wb2[(du_c * 32 + i) * ZD + du_k];

    double wd2r_d[8];
    {
        float4 a0 = reinterpret_cast<const float4*>(Wd2 + (size_t)j * 8)[0];
        float4 a1 = reinterpret_cast<const float4*>(Wd2 + (size_t)j * 8)[1];
        wd2r_d[0] = (double)a0.x; wd2r_d[1] = (double)a0.y;
        wd2r_d[2] = (double)a0.z; wd2r_d[3] = (double)a0.w;
        wd2r_d[4] = (double)a1.x; wd2r_d[5] = (double)a1.y;
        wd2r_d[6] = (double)a1.z; wd2r_d[7] = (double)a1.w;
    }
    if (g == 0) {
#pragma unroll
        for (int yd = 0; yd < 8; yd++) sm.wd2t_d[yd][j] = wd2r_d[yd];
#pragma unroll
        for (int kk = 0; kk < 32; kk++)
            sm.wd1zT[j * 64 + (kk ^ (j & 63))] = wd1z[kk];
    } else {
#pragma unroll
        for (int kk = 0; kk < 32; kk++)
            sm.wd1zT[j * 64 + ((32 + kk) ^ (j & 63))] = wd1z[32 + kk];
    }
    const double bd1_d = (double)bd1[j];

    __syncthreads();

    // ---------------- encoder (once, f64) ----------------
    if (tid < 256) {
        float we1r[16];
#pragma unroll
        for (int k = 0; k < 16; k++) we1r[k] = We1[k * HID + j];
        double be1_d = (double)be1[j];
        double msum = 0.0;
        for (int n = 0; n < NN_; n++) msum += (double)sm.m_s[n];
        msum = fmax(msum, 1.0);
        double pacc = 0.0;
        for (int n = 0; n < NN_; n++) {
            double pre = be1_d;
#pragma unroll
            for (int k = 0; k < 8; k++) pre = fma((double)sm.x_s[n][k], (double)we1r[k], pre);
#pragma unroll
            for (int k = 0; k < 8; k++) pre = fma((double)sm.y_s[n][k], (double)we1r[8 + k], pre);
            pacc += gelu_d(pre) * (double)sm.m_s[n];
        }
        sm.hb_ds[j] = pacc / msum;       // pooled
    }
    __syncthreads();
    if (tid < 256) {
        int i = tid & 127, half = tid >> 7;
        double racc = 0.0;
        for (int jj = half * 128; jj < half * 128 + 128; jj++)
            racc = fma(sm.hb_ds[jj], (double)We2[jj * RD + i], racc);
        sm.scratch2[half][i] = racc;
    }
    __syncthreads();
    if (tid < RD) r_d[tid] = sm.scratch2[0][tid] + sm.scratch2[1][tid] + (double)be2[tid];
    __syncthreads();

    double hbr = 0.0, wb1t_d = 0.0;
    if (tid < 256) {                     // step-invariant drift-hidden part
        hbr = (double)bb1[j];
        for (int k = 0; k < RD; k++)
            hbr = fma(r_d[k], (double)Wb1[(ZD + k) * HID + j], hbr);
        wb1t_d = (double)Wb1[(ZD + RD) * HID + j];
    }
    __syncthreads();                     // r_d (res_r alias) free after this

    // ---------------- main 50-step loop ----------------
    const double dt  = 1.0 / (double)NSTEPS;
    const double nsc = sqrt(2.0 * 1.0 * dt);

    for (int s = 0; s < NSTEPS; s++) {
        const double t = (double)s * dt;

        // prefetch this step's noise early (consumed only at the z-update)
        float nzf = 0.0f;
        if (tid < ZD) nzf = noise[((size_t)s * BB + b) * ZD + tid];

        // zdot (per-thread; x-part handled in tiles)
        double zd0 = 0.0, zd1 = 0.0;
#pragma unroll
        for (int k = 0; k < 64; k += 2) {
            zd0 = fma(sm.z_ds[k],     (double)wd1z[k],     zd0);
            zd1 = fma(sm.z_ds[k + 1], (double)wd1z[k + 1], zd1);
        }
        const double zpre = bd1_d + zd0 + zd1;

        // ---- phase A: drift hidden partials (k-split across g, reg weights) ----
        {
            double a0 = 0.0;
            const int kb = g * 32;
#pragma unroll
            for (int kk = 0; kk < 32; kk++)
                a0 = fma(sm.z_ds[kb + kk], (double)wb1_r[kk], a0);
            sm.scratch2[g][j] = a0;
        }
        __syncthreads();
        if (tid < 256) {
            double hacc = hbr + t * wb1t_d + sm.scratch2[0][j] + sm.scratch2[1][j];
            sm.hb_ds[j] = gelu_d(hacc);
        }
        __syncthreads();
        // ---- drift out partials (reg weights; consumed at update) ----
        {
            double acc = 0.0;
#pragma unroll
            for (int i = 0; i < 32; i++)
                acc = fma(sm.hb_ds[du_c * 32 + i], (double)wb2_r[i], acc);
            sm.bp_d[du_c][du_k] = acc;
        }

        // ---- decode fwd+bwd: 8 tiles x 16 rows (rows split across g) ----
        double S = 0.0;                  // sum_n dpre[n][j] (this thread's row-half)
        for (int tile = 0; tile < NTILES; tile++) {
            const int base = tile * NT;
            const int rb = g * 8;
            // F: hidden + gelu'
#pragma unroll
            for (int nn = 0; nn < 8; nn++) {
                const int row = rb + nn;
                const float4 xa = *reinterpret_cast<const float4*>(&sm.x_s[base + row][0]);
                const float4 xb = *reinterpret_cast<const float4*>(&sm.x_s[base + row][4]);
                double pre = zpre;
                pre = fma((double)xa.x, wd1x_d[0], pre);
                pre = fma((double)xa.y, wd1x_d[1], pre);
                pre = fma((double)xa.z, wd1x_d[2], pre);
                pre = fma((double)xa.w, wd1x_d[3], pre);
                pre = fma((double)xb.x, wd1x_d[4], pre);
                pre = fma((double)xb.y, wd1x_d[5], pre);
                pre = fma((double)xb.z, wd1x_d[6], pre);
                pre = fma((double)xb.w, wd1x_d[7], pre);
                double h, gp;
                gelu_both_d(pre, h, gp);
                sm.h_t[row][j]  = h;
                sm.gp_t[row][j] = (float)gp;
            }
            __syncthreads();
            // M: mu partials over j-quarters (double2 LDS reads, conflict-free)
            {
                const int q = tid >> 7, pair = tid & 127;
                const int nn = pair >> 3, yd = pair & 7;
                const double2* hrow = reinterpret_cast<const double2*>(&sm.h_t[nn][q * 64]);
                const double2* wrow = reinterpret_cast<const double2*>(&sm.wd2t_d[yd][q * 64]);
                double a0 = 0.0, a1 = 0.0;
#pragma unroll
                for (int i = 0; i < 32; i++) {
                    double2 hv = hrow[i], wv = wrow[i];
                    a0 = fma(hv.x, wv.x, a0);
                    a1 = fma(hv.y, wv.y, a1);
                }
                sm.pmgz[q * 128 + pair] = a0 + a1;
            }
            __syncthreads();
            // R: residual
            if (tid < 128) {
                const int nn = tid >> 3, yd = tid & 7;
                double mu = sm.pmgz[tid] + sm.pmgz[128 + tid] + sm.pmgz[256 + tid]
                          + sm.pmgz[384 + tid] + sm.bd2_d[yd];
                sm.res_r[nn][yd] = 4.0 * t * (mu - (double)sm.y_s[base + nn][yd])
                                           * (double)sm.m_s[base + nn];
            }
            __syncthreads();
            // B: S += dpre over this thread's row-half
#pragma unroll
            for (int nn = 0; nn < 8; nn++) {
                const int row = rb + nn;
                const double2* rr = reinterpret_cast<const double2*>(&sm.res_r[row][0]);
                double2 r0 = rr[0], r1 = rr[1], r2 = rr[2], r3 = rr[3];
                double dh = r0.x * wd2r_d[0] + r0.y * wd2r_d[1]
                          + r1.x * wd2r_d[2] + r1.y * wd2r_d[3]
                          + r2.x * wd2r_d[4] + r2.y * wd2r_d[5]
                          + r3.x * wd2r_d[6] + r3.y * wd2r_d[7];
                S = fma(dh, (double)sm.gp_t[row][j], S);
            }
            __syncthreads();
        }

        // ---- gradient: gz[k] = sum_j Ssum_j * Wd1z[k][j] via LDS matvec ----
        sm.scratch2[g][j] = S;
        __syncthreads();
        if (tid < 256) sm.hb_ds[j] = sm.scratch2[0][j] + sm.scratch2[1][j];  // Ssum
        __syncthreads();
        {
            const int k = tid & 63, c = tid >> 6;
            double acc = 0.0;
#pragma unroll
            for (int i = 0; i < 32; i++) {
                const int jj = c * 32 + i;
                acc = fma(sm.hb_ds[jj],
                          (double)sm.wd1zT[jj * 64 + (k ^ (jj & 63))], acc);
            }
            sm.pmgz[c * 64 + k] = acc;   // gzp
        }
        __syncthreads();
        // ---- z update ----
        if (tid < ZD) {
            double gsum = sm.z_ds[tid];
#pragma unroll
            for (int c = 0; c < 8; c++) gsum += sm.pmgz[c * 64 + tid];
            gsum = fmin(fmax(gsum, -100.0), 100.0);
            double bdr = sm.bb2_d[tid];
#pragma unroll
            for (int c = 0; c < 8; c++) bdr += sm.bp_d[c][tid];
            sm.z_ds[tid] = sm.z_ds[tid] + (bdr - gsum) * dt + nsc * (double)nzf;
        }
        __syncthreads();
    }

    if (tid < ZD) out[(size_t)b * ZD + tid] = (float)sm.z_ds[tid];
}

extern "C" void kernel_launch(void* const* d_in, const int* in_sizes, int n_in,
                              void* d_out, int out_size, void* d_ws, size_t ws_size,
                              hipStream_t stream) {
    const float* x_ctx = (const float*)d_in[0];
    const float* y_ctx = (const float*)d_in[1];
    const float* maskp = (const float*)d_in[2];
    const float* z0    = (const float*)d_in[3];
    const float* noise = (const float*)d_in[4];
    const float* We1   = (const float*)d_in[5];
    const float* be1   = (const float*)d_in[6];
    const float* We2   = (const float*)d_in[7];
    const float* be2   = (const float*)d_in[8];
    const float* Wd1   = (const float*)d_in[9];
    const float* bd1   = (const float*)d_in[10];
    const float* Wd2   = (const float*)d_in[11];
    const float* bd2   = (const float*)d_in[12];
    const float* Wb1   = (const float*)d_in[13];
    const float* bb1   = (const float*)d_in[14];
    const float* Wb2   = (const float*)d_in[15];
    const float* bb2   = (const float*)d_in[16];
    float* out = (float*)d_out;

    (void)hipFuncSetAttribute((const void*)nets_sampler_kernel,
                              hipFuncAttributeMaxDynamicSharedMemorySize,
                              (int)sizeof(Smem));

    nets_sampler_kernel<<<BB, TPB, sizeof(Smem), stream>>>(
        x_ctx, y_ctx, maskp, z0, noise,
        We1, be1, We2, be2, Wd1, bd1, Wd2, bd2, Wb1, bb1, Wb2, bb2, out);
}